// Round 3
// baseline (713.833 us; speedup 1.0000x reference)
//
#include <hip/hip_runtime.h>
#include <math.h>

#define N_NODES 5000
#define E_EDGES 160000
#define H_HEADS 6
#define D_FEAT  64
#define IN_FEAT 131
#define HD      384          // H*D
#define NC4     (N_NODES/4)  // 1250
#define AGG_CAP 1024         // max edges staged in LDS per node (fallback path beyond)
#define KSPLIT  2

// ---------------- CSR build ----------------
__global__ void k_count(const int* __restrict__ dst, int* __restrict__ deg) {
    int e = blockIdx.x * blockDim.x + threadIdx.x;
    if (e < E_EDGES) atomicAdd(&deg[dst[e]], 1);
}

// single block, 1024 threads: exclusive scan of deg[0..N) -> row_ptr, zero deg (reused as cursor)
__global__ void k_scan(int* __restrict__ deg, int* __restrict__ row_ptr) {
    __shared__ int part[1024];
    const int T = 1024;
    int t = threadIdx.x;
    const int per = (N_NODES + T - 1) / T;   // 5
    int start = t * per;
    int s = 0;
    for (int i = 0; i < per; i++) {
        int idx = start + i;
        if (idx < N_NODES) s += deg[idx];
    }
    part[t] = s;
    __syncthreads();
    for (int off = 1; off < T; off <<= 1) {
        int v = (t >= off) ? part[t - off] : 0;
        __syncthreads();
        part[t] += v;
        __syncthreads();
    }
    int excl = (t == 0) ? 0 : part[t - 1];
    for (int i = 0; i < per; i++) {
        int idx = start + i;
        if (idx < N_NODES) {
            row_ptr[idx] = excl;
            excl += deg[idx];
            deg[idx] = 0;     // reset as fill cursor
        }
    }
    if (t == T - 1) row_ptr[N_NODES] = part[T - 1];
}

// store SOURCE NODE ID directly (edge identity never needed downstream)
__global__ void k_fill(const int* __restrict__ src, const int* __restrict__ dst,
                       const int* __restrict__ row_ptr,
                       int* __restrict__ cursor, int* __restrict__ csrc) {
    int e = blockIdx.x * blockDim.x + threadIdx.x;
    if (e < E_EDGES) {
        int d = dst[e];
        int p = atomicAdd(&cursor[d], 1);
        csrc[row_ptr[d] + p] = src[e];
    }
}

// ---------------- fp32 SGEMM with K-split: C[M,384] += A[M,K] @ W[K,384] ----------------
// grid (HD/64, ceil(M/64), KSPLIT); C must be zeroed before launch (atomic accumulate).
__global__ __launch_bounds__(256) void k_gemm(const float* __restrict__ A,
                                              const float* __restrict__ W,
                                              float* __restrict__ C, int M, int K) {
    const int BM = 64, BN = 64, BK = 16;
    __shared__ float As[BK][BM + 4];   // +4 pad keeps 16B alignment (272B stride)
    __shared__ float Bs[BK][BN + 4];
    int bx = blockIdx.x;          // N tile (0..5)
    int by = blockIdx.y;          // M tile
    int kb = blockIdx.z;          // K slice
    int kh = (K + KSPLIT - 1) / KSPLIT;
    int kbeg = kb * kh;
    int kend = min(K, kbeg + kh);
    int tid = threadIdx.x;
    int tx = tid & 15, ty = tid >> 4;
    float acc[4][4] = {};
    int rowBase = by * BM;
    int arow = tid >> 2, acol = (tid & 3) * 4;      // A: 64 rows x 16 k, float4/thread
    int bkr = tid >> 4, bnc = (tid & 15) * 4;       // B: 16 k x 64 n, float4/thread
    const bool kvec = ((K & 3) == 0);               // layer0 K=131 -> scalar A loads
    for (int k0 = kbeg; k0 < kend; k0 += BK) {
        {   // stage A (zero-fill beyond edges -> inner loop needs no guards)
            int gr = rowBase + arow, gk = k0 + acol;
            float4 v = {0.f, 0.f, 0.f, 0.f};
            if (gr < M) {
                if (kvec && gk + 3 < kend) {
                    v = *(const float4*)(A + (size_t)gr * K + gk);
                } else {
                    float* vv = (float*)&v;
#pragma unroll
                    for (int q = 0; q < 4; q++)
                        if (gk + q < kend) vv[q] = A[(size_t)gr * K + gk + q];
                }
            }
            As[acol + 0][arow] = v.x;
            As[acol + 1][arow] = v.y;
            As[acol + 2][arow] = v.z;
            As[acol + 3][arow] = v.w;
        }
        {   // stage B
            int gk = k0 + bkr;
            float4 v = {0.f, 0.f, 0.f, 0.f};
            if (gk < kend) v = *(const float4*)(W + (size_t)gk * HD + bx * BN + bnc);
            *(float4*)&Bs[bkr][bnc] = v;
        }
        __syncthreads();
#pragma unroll
        for (int k = 0; k < BK; k++) {
            float4 a = *(const float4*)&As[k][ty * 4];
            float4 b = *(const float4*)&Bs[k][tx * 4];
            const float* ap = (const float*)&a;
            const float* bp = (const float*)&b;
#pragma unroll
            for (int i = 0; i < 4; i++)
#pragma unroll
                for (int j = 0; j < 4; j++) acc[i][j] += ap[i] * bp[j];
        }
        __syncthreads();
    }
#pragma unroll
    for (int i = 0; i < 4; i++) {
        int gr = rowBase + ty * 4 + i;
        if (gr < M) {
#pragma unroll
            for (int j = 0; j < 4; j++)
                atomicAdd(&C[(size_t)gr * HD + bx * BN + tx * 4 + j], acc[i][j]);
        }
    }
}

// ---------------- el/er: per-(node,head) dot over D ----------------
__global__ void k_elr(const float* __restrict__ f, const float* __restrict__ al,
                      const float* __restrict__ ar, float* __restrict__ el,
                      float* __restrict__ er) {
    int wave = (blockIdx.x * blockDim.x + threadIdx.x) >> 6;
    int lane = threadIdx.x & 63;
    if (wave >= N_NODES * H_HEADS) return;
    int n = wave / H_HEADS, h = wave % H_HEADS;
    float v = f[n * HD + h * D_FEAT + lane];
    float pl = v * al[h * D_FEAT + lane];
    float pr = v * ar[h * D_FEAT + lane];
    for (int off = 32; off; off >>= 1) {
        pl += __shfl_down(pl, off);
        pr += __shfl_down(pr, off);
    }
    if (lane == 0) { el[wave] = pl; er[wave] = pr; }
}

// ---------------- per-dst softmax + weighted gather-sum (LDS-staged) ----------------
__global__ __launch_bounds__(384) void k_agg(const float* __restrict__ f,
                                             const float* __restrict__ el,
                                             const float* __restrict__ er,
                                             const float* __restrict__ bias,
                                             const int* __restrict__ row_ptr,
                                             const int* __restrict__ csrc,
                                             float* __restrict__ out, int activate) {
    __shared__ int   s_src[AGG_CAP];
    __shared__ float s_x[AGG_CAP * H_HEADS];
    __shared__ float sh_inv[H_HEADS];
    int node = blockIdx.x;
    int t = threadIdx.x;
    int h = t >> 6, lane = t & 63;
    int r0 = row_ptr[node], r1 = row_ptr[node + 1];
    int deg = r1 - r0;
    int dcap = deg < AGG_CAP ? deg : AGG_CAP;
    float er_h = er[node * H_HEADS + h];

    // stage src ids (all 384 threads)
    for (int i = t; i < dcap; i += 384) s_src[i] = csrc[r0 + i];
    __syncthreads();

    // per-head: compute leaky scores into LDS + running max (wave h, lanes over edges)
    float m = -1e30f;
    for (int i = lane; i < dcap; i += 64) {
        int s = s_src[i];
        float x = el[s * H_HEADS + h] + er_h;
        x = x >= 0.f ? x : 0.2f * x;
        s_x[i * H_HEADS + h] = x;
        m = fmaxf(m, x);
    }
    for (int i = AGG_CAP + lane; i < deg; i += 64) {   // rare tail (deg > CAP)
        int s = csrc[r0 + i];
        float x = el[s * H_HEADS + h] + er_h;
        x = x >= 0.f ? x : 0.2f * x;
        m = fmaxf(m, x);
    }
    for (int off = 32; off; off >>= 1) m = fmaxf(m, __shfl_down(m, off));
    m = __shfl(m, 0);

    // sum of exp; overwrite s_x with unnormalized weight
    float ssum = 0.f;
    for (int i = lane; i < dcap; i += 64) {
        float w = __expf(s_x[i * H_HEADS + h] - m);
        s_x[i * H_HEADS + h] = w;
        ssum += w;
    }
    for (int i = AGG_CAP + lane; i < deg; i += 64) {
        int s = csrc[r0 + i];
        float x = el[s * H_HEADS + h] + er_h;
        x = x >= 0.f ? x : 0.2f * x;
        ssum += __expf(x - m);
    }
    for (int off = 32; off; off >>= 1) ssum += __shfl_down(ssum, off);
    if (lane == 0) sh_inv[h] = (ssum > 0.f) ? 1.f / ssum : 0.f;
    __syncthreads();
    float inv = sh_inv[h];

    // accumulate: thread (h,lane) sums w * f[src, h, lane]; LDS reads are broadcasts
    const float* fh = f + h * D_FEAT + lane;
    float acc = 0.f;
    int i = 0;
    int lim = dcap & ~3;
    for (; i < lim; i += 4) {
        int s0 = s_src[i], s1 = s_src[i + 1], s2 = s_src[i + 2], s3 = s_src[i + 3];
        float w0 = s_x[(i) * H_HEADS + h];
        float w1 = s_x[(i + 1) * H_HEADS + h];
        float w2 = s_x[(i + 2) * H_HEADS + h];
        float w3 = s_x[(i + 3) * H_HEADS + h];
        float f0 = fh[(size_t)s0 * HD];
        float f1 = fh[(size_t)s1 * HD];
        float f2 = fh[(size_t)s2 * HD];
        float f3 = fh[(size_t)s3 * HD];
        acc += w0 * f0; acc += w1 * f1; acc += w2 * f2; acc += w3 * f3;
    }
    for (; i < dcap; i++) {
        acc += s_x[i * H_HEADS + h] * fh[(size_t)s_src[i] * HD];
    }
    for (i = AGG_CAP; i < deg; i++) {                  // rare tail
        int s = csrc[r0 + i];
        float x = el[s * H_HEADS + h] + er_h;
        x = x >= 0.f ? x : 0.2f * x;
        acc += __expf(x - m) * fh[(size_t)s * HD];
    }
    float o = acc * inv + bias[h * D_FEAT + lane];
    if (activate) o = o > 0.f ? o : (__expf(o) - 1.f);
    out[node * HD + h * D_FEAT + lane] = o;
}

// ---------------- head-mean + two dots with pw ----------------
__global__ void k_embed(const float* __restrict__ h3, const float* __restrict__ pw,
                        float* __restrict__ s1, float* __restrict__ s2) {
    int wave = (blockIdx.x * blockDim.x + threadIdx.x) >> 6;
    int lane = threadIdx.x & 63;
    if (wave >= N_NODES) return;
    float s = 0.f;
#pragma unroll
    for (int hh = 0; hh < H_HEADS; hh++) s += h3[wave * HD + hh * D_FEAT + lane];
    s *= (1.f / 6.f);
    float p1 = s * pw[lane];
    float p2 = s * pw[D_FEAT + lane];
    for (int off = 32; off; off >>= 1) {
        p1 += __shfl_down(p1, off);
        p2 += __shfl_down(p2, off);
    }
    if (lane == 0) { s1[wave] = p1; s2[wave] = p2; }
}

// ---------------- pairwise tanh output ----------------
__global__ void k_pair(const float4* __restrict__ dis, const float* __restrict__ s1,
                       const float* __restrict__ s2, const float* __restrict__ pw,
                       const float* __restrict__ pb, float4* __restrict__ out) {
    const int total = N_NODES * NC4;
    float w = pw[2 * D_FEAT];
    float b = pb[0];
    for (int idx = blockIdx.x * blockDim.x + threadIdx.x; idx < total;
         idx += gridDim.x * blockDim.x) {
        int i = idx / NC4;
        int j4 = idx - i * NC4;
        float4 dv = dis[idx];
        float base = s2[i] + b;
        int j = j4 * 4;
        float4 o;
        o.x = tanhf(base + s1[j + 0] + dv.x * w);
        o.y = tanhf(base + s1[j + 1] + dv.y * w);
        o.z = tanhf(base + s1[j + 2] + dv.z * w);
        o.w = tanhf(base + s1[j + 3] + dv.w * w);
        out[idx] = o;
    }
}

extern "C" void kernel_launch(void* const* d_in, const int* in_sizes, int n_in,
                              void* d_out, int out_size, void* d_ws, size_t ws_size,
                              hipStream_t stream) {
    const float* nfeats = (const float*)d_in[0];
    const float* dis    = (const float*)d_in[1];
    const int*   src    = (const int*)d_in[2];
    const int*   dst    = (const int*)d_in[3];
    const float* w[4]  = {(const float*)d_in[4],  (const float*)d_in[8],
                          (const float*)d_in[12], (const float*)d_in[16]};
    const float* al[4] = {(const float*)d_in[5],  (const float*)d_in[9],
                          (const float*)d_in[13], (const float*)d_in[17]};
    const float* ar[4] = {(const float*)d_in[6],  (const float*)d_in[10],
                          (const float*)d_in[14], (const float*)d_in[18]};
    const float* bs[4] = {(const float*)d_in[7],  (const float*)d_in[11],
                          (const float*)d_in[15], (const float*)d_in[19]};
    const float* pw = (const float*)d_in[20];
    const float* pb = (const float*)d_in[21];
    float* out = (float*)d_out;

    // workspace layout
    float* f    = (float*)d_ws;                 // N*HD
    float* hbuf = f + N_NODES * HD;             // N*HD
    float* el   = hbuf + N_NODES * HD;          // N*H
    float* er   = el + N_NODES * H_HEADS;       // N*H
    float* s1   = er + N_NODES * H_HEADS;       // N
    float* s2   = s1 + N_NODES;                 // N
    int* row_ptr = (int*)(s2 + N_NODES);        // N+1
    int* cursor  = row_ptr + (N_NODES + 1);     // N
    int* csrc    = cursor + N_NODES;            // E (source node id, grouped by dst)

    // CSR build (dst-indexed)
    hipMemsetAsync(cursor, 0, N_NODES * sizeof(int), stream);
    k_count<<<(E_EDGES + 255) / 256, 256, 0, stream>>>(dst, cursor);
    k_scan<<<1, 1024, 0, stream>>>(cursor, row_ptr);
    k_fill<<<(E_EDGES + 255) / 256, 256, 0, stream>>>(src, dst, row_ptr, cursor, csrc);

    const float* hin = nfeats;
    for (int l = 0; l < 4; l++) {
        int K = (l == 0) ? IN_FEAT : HD;
        hipMemsetAsync(f, 0, N_NODES * HD * sizeof(float), stream);  // atomic-accumulate target
        dim3 g(HD / 64, (N_NODES + 63) / 64, KSPLIT);
        k_gemm<<<g, 256, 0, stream>>>(hin, w[l], f, N_NODES, K);
        k_elr<<<(N_NODES * H_HEADS + 3) / 4, 256, 0, stream>>>(f, al[l], ar[l], el, er);
        k_agg<<<N_NODES, 384, 0, stream>>>(f, el, er, bs[l], row_ptr, csrc, hbuf,
                                           (l < 3) ? 1 : 0);
        hin = hbuf;
    }
    k_embed<<<(N_NODES + 3) / 4, 256, 0, stream>>>(hbuf, pw, s1, s2);
    k_pair<<<4096, 256, 0, stream>>>((const float4*)dis, s1, s2, pw, pb, (float4*)out);
}

// Round 4
// 616.286 us; speedup vs baseline: 1.1583x; 1.1583x over previous
//
#include <hip/hip_runtime.h>
#include <math.h>

#define N_NODES 5000
#define E_EDGES 160000
#define H_HEADS 6
#define D_FEAT  64
#define IN_FEAT 131
#define HD      384          // H*D
#define NC4     (N_NODES/4)  // 1250
#define AGG_CAP 1024         // max edges staged in LDS per node (fallback path beyond)

// ---------------- CSR build ----------------
__global__ void k_count(const int* __restrict__ dst, int* __restrict__ deg) {
    int e = blockIdx.x * blockDim.x + threadIdx.x;
    if (e < E_EDGES) atomicAdd(&deg[dst[e]], 1);
}

// single block, 1024 threads: exclusive scan of deg[0..N) -> row_ptr, zero deg (reused as cursor)
__global__ void k_scan(int* __restrict__ deg, int* __restrict__ row_ptr) {
    __shared__ int part[1024];
    const int T = 1024;
    int t = threadIdx.x;
    const int per = (N_NODES + T - 1) / T;   // 5
    int start = t * per;
    int s = 0;
    for (int i = 0; i < per; i++) {
        int idx = start + i;
        if (idx < N_NODES) s += deg[idx];
    }
    part[t] = s;
    __syncthreads();
    for (int off = 1; off < T; off <<= 1) {
        int v = (t >= off) ? part[t - off] : 0;
        __syncthreads();
        part[t] += v;
        __syncthreads();
    }
    int excl = (t == 0) ? 0 : part[t - 1];
    for (int i = 0; i < per; i++) {
        int idx = start + i;
        if (idx < N_NODES) {
            row_ptr[idx] = excl;
            excl += deg[idx];
            deg[idx] = 0;     // reset as fill cursor
        }
    }
    if (t == T - 1) row_ptr[N_NODES] = part[T - 1];
}

// store SOURCE NODE ID directly (edge identity never needed downstream)
__global__ void k_fill(const int* __restrict__ src, const int* __restrict__ dst,
                       const int* __restrict__ row_ptr,
                       int* __restrict__ cursor, int* __restrict__ csrc) {
    int e = blockIdx.x * blockDim.x + threadIdx.x;
    if (e < E_EDGES) {
        int d = dst[e];
        int p = atomicAdd(&cursor[d], 1);
        csrc[row_ptr[d] + p] = src[e];
    }
}

// ---------------- fp32 SGEMM, single-wave 32x32 tile: C[M,384] = A[M,K] @ W[K,384] ----
// grid (HD/32=12, ceil(M/32)); 64 threads (ONE wave) per block -> barriers are free,
// 1884 blocks give ~7 blocks/CU so LDS/VMEM latency is hidden by sibling waves.
__global__ __launch_bounds__(64, 8) void k_gemm(const float* __restrict__ A,
                                                const float* __restrict__ W,
                                                float* __restrict__ C, int M, int K) {
    const int BM = 32, BN = 32, BK = 32;
    __shared__ float As[BK][BM + 4];   // +4: keeps float4 alignment (144B stride)
    __shared__ float Bs[BK][BN + 4];
    int bx = blockIdx.x;          // n tile (0..11)
    int by = blockIdx.y;          // m tile
    int tid = threadIdx.x;        // 0..63
    int tx = tid & 7, ty = tid >> 3;      // 8x8 threads, each 4x4 outputs
    int rowBase = by * BM;
    int colBase = bx * BN;
    float acc[4][4] = {};
    const bool kvec = ((K & 3) == 0);     // layer0 K=131 -> guarded scalar A loads
    for (int k0 = 0; k0 < K; k0 += BK) {
        // stage A: 32 rows x 32 k. thread -> rows (tid>>3)+8i, k-chunk (tid&7)*4
#pragma unroll
        for (int i = 0; i < 4; i++) {
            int m = (tid >> 3) + 8 * i;
            int gr = rowBase + m;
            int gk = k0 + (tid & 7) * 4;
            float4 v = {0.f, 0.f, 0.f, 0.f};
            if (gr < M) {
                if (kvec && gk + 3 < K) {
                    v = *(const float4*)(A + (size_t)gr * K + gk);
                } else {
                    float* vv = (float*)&v;
#pragma unroll
                    for (int q = 0; q < 4; q++)
                        if (gk + q < K) vv[q] = A[(size_t)gr * K + gk + q];
                }
            }
            int kk = (tid & 7) * 4;
            As[kk + 0][m] = v.x;
            As[kk + 1][m] = v.y;
            As[kk + 2][m] = v.z;
            As[kk + 3][m] = v.w;
        }
        // stage B: 32 k x 32 n. thread -> k-rows (tid>>3)+8i, n-chunk (tid&7)*4
#pragma unroll
        for (int i = 0; i < 4; i++) {
            int kr = (tid >> 3) + 8 * i;
            int gk = k0 + kr;
            float4 v = {0.f, 0.f, 0.f, 0.f};
            if (gk < K) v = *(const float4*)(W + (size_t)gk * HD + colBase + (tid & 7) * 4);
            *(float4*)&Bs[kr][(tid & 7) * 4] = v;
        }
        __syncthreads();
#pragma unroll 8
        for (int k = 0; k < BK; k++) {
            float4 a = *(const float4*)&As[k][ty * 4];
            float4 b = *(const float4*)&Bs[k][tx * 4];
            const float* ap = (const float*)&a;
            const float* bp = (const float*)&b;
#pragma unroll
            for (int i = 0; i < 4; i++)
#pragma unroll
                for (int j = 0; j < 4; j++) acc[i][j] += ap[i] * bp[j];
        }
        __syncthreads();
    }
#pragma unroll
    for (int i = 0; i < 4; i++) {
        int gr = rowBase + ty * 4 + i;
        if (gr < M) {
            float4 v = {acc[i][0], acc[i][1], acc[i][2], acc[i][3]};
            *(float4*)(C + (size_t)gr * HD + colBase + tx * 4) = v;
        }
    }
}

// ---------------- el/er: per-(node,head) dot over D ----------------
__global__ void k_elr(const float* __restrict__ f, const float* __restrict__ al,
                      const float* __restrict__ ar, float* __restrict__ el,
                      float* __restrict__ er) {
    int wave = (blockIdx.x * blockDim.x + threadIdx.x) >> 6;
    int lane = threadIdx.x & 63;
    if (wave >= N_NODES * H_HEADS) return;
    int n = wave / H_HEADS, h = wave % H_HEADS;
    float v = f[n * HD + h * D_FEAT + lane];
    float pl = v * al[h * D_FEAT + lane];
    float pr = v * ar[h * D_FEAT + lane];
    for (int off = 32; off; off >>= 1) {
        pl += __shfl_down(pl, off);
        pr += __shfl_down(pr, off);
    }
    if (lane == 0) { el[wave] = pl; er[wave] = pr; }
}

// ---------------- per-dst softmax + weighted gather-sum (LDS-staged) ----------------
__global__ __launch_bounds__(384) void k_agg(const float* __restrict__ f,
                                             const float* __restrict__ el,
                                             const float* __restrict__ er,
                                             const float* __restrict__ bias,
                                             const int* __restrict__ row_ptr,
                                             const int* __restrict__ csrc,
                                             float* __restrict__ out, int activate) {
    __shared__ int   s_src[AGG_CAP];
    __shared__ float s_x[AGG_CAP * H_HEADS];
    __shared__ float sh_inv[H_HEADS];
    int node = blockIdx.x;
    int t = threadIdx.x;
    int h = t >> 6, lane = t & 63;
    int r0 = row_ptr[node], r1 = row_ptr[node + 1];
    int deg = r1 - r0;
    int dcap = deg < AGG_CAP ? deg : AGG_CAP;
    float er_h = er[node * H_HEADS + h];

    // stage src ids (all 384 threads)
    for (int i = t; i < dcap; i += 384) s_src[i] = csrc[r0 + i];
    __syncthreads();

    // per-head: compute leaky scores into LDS + running max (wave h, lanes over edges)
    float m = -1e30f;
    for (int i = lane; i < dcap; i += 64) {
        int s = s_src[i];
        float x = el[s * H_HEADS + h] + er_h;
        x = x >= 0.f ? x : 0.2f * x;
        s_x[i * H_HEADS + h] = x;
        m = fmaxf(m, x);
    }
    for (int i = AGG_CAP + lane; i < deg; i += 64) {   // rare tail (deg > CAP)
        int s = csrc[r0 + i];
        float x = el[s * H_HEADS + h] + er_h;
        x = x >= 0.f ? x : 0.2f * x;
        m = fmaxf(m, x);
    }
    for (int off = 32; off; off >>= 1) m = fmaxf(m, __shfl_down(m, off));
    m = __shfl(m, 0);

    // sum of exp; overwrite s_x with unnormalized weight
    float ssum = 0.f;
    for (int i = lane; i < dcap; i += 64) {
        float w = __expf(s_x[i * H_HEADS + h] - m);
        s_x[i * H_HEADS + h] = w;
        ssum += w;
    }
    for (int i = AGG_CAP + lane; i < deg; i += 64) {
        int s = csrc[r0 + i];
        float x = el[s * H_HEADS + h] + er_h;
        x = x >= 0.f ? x : 0.2f * x;
        ssum += __expf(x - m);
    }
    for (int off = 32; off; off >>= 1) ssum += __shfl_down(ssum, off);
    if (lane == 0) sh_inv[h] = (ssum > 0.f) ? 1.f / ssum : 0.f;
    __syncthreads();
    float inv = sh_inv[h];

    // accumulate: thread (h,lane) sums w * f[src, h, lane]; 8 gathers in flight
    const float* fh = f + h * D_FEAT + lane;
    float acc = 0.f;
    int i = 0;
    int lim = dcap & ~7;
    for (; i < lim; i += 8) {
        int s0 = s_src[i + 0], s1 = s_src[i + 1], s2 = s_src[i + 2], s3 = s_src[i + 3];
        int s4 = s_src[i + 4], s5 = s_src[i + 5], s6 = s_src[i + 6], s7 = s_src[i + 7];
        float f0 = fh[(size_t)s0 * HD], f1 = fh[(size_t)s1 * HD];
        float f2 = fh[(size_t)s2 * HD], f3 = fh[(size_t)s3 * HD];
        float f4 = fh[(size_t)s4 * HD], f5 = fh[(size_t)s5 * HD];
        float f6 = fh[(size_t)s6 * HD], f7 = fh[(size_t)s7 * HD];
        acc += s_x[(i + 0) * H_HEADS + h] * f0;
        acc += s_x[(i + 1) * H_HEADS + h] * f1;
        acc += s_x[(i + 2) * H_HEADS + h] * f2;
        acc += s_x[(i + 3) * H_HEADS + h] * f3;
        acc += s_x[(i + 4) * H_HEADS + h] * f4;
        acc += s_x[(i + 5) * H_HEADS + h] * f5;
        acc += s_x[(i + 6) * H_HEADS + h] * f6;
        acc += s_x[(i + 7) * H_HEADS + h] * f7;
    }
    for (; i < dcap; i++) {
        acc += s_x[i * H_HEADS + h] * fh[(size_t)s_src[i] * HD];
    }
    for (i = AGG_CAP; i < deg; i++) {                  // rare tail
        int s = csrc[r0 + i];
        float x = el[s * H_HEADS + h] + er_h;
        x = x >= 0.f ? x : 0.2f * x;
        acc += __expf(x - m) * fh[(size_t)s * HD];
    }
    float o = acc * inv + bias[h * D_FEAT + lane];
    if (activate) o = o > 0.f ? o : (__expf(o) - 1.f);
    out[node * HD + h * D_FEAT + lane] = o;
}

// ---------------- head-mean + two dots with pw ----------------
__global__ void k_embed(const float* __restrict__ h3, const float* __restrict__ pw,
                        float* __restrict__ s1, float* __restrict__ s2) {
    int wave = (blockIdx.x * blockDim.x + threadIdx.x) >> 6;
    int lane = threadIdx.x & 63;
    if (wave >= N_NODES) return;
    float s = 0.f;
#pragma unroll
    for (int hh = 0; hh < H_HEADS; hh++) s += h3[wave * HD + hh * D_FEAT + lane];
    s *= (1.f / 6.f);
    float p1 = s * pw[lane];
    float p2 = s * pw[D_FEAT + lane];
    for (int off = 32; off; off >>= 1) {
        p1 += __shfl_down(p1, off);
        p2 += __shfl_down(p2, off);
    }
    if (lane == 0) { s1[wave] = p1; s2[wave] = p2; }
}

// ---------------- pairwise tanh output ----------------
__global__ void k_pair(const float4* __restrict__ dis, const float* __restrict__ s1,
                       const float* __restrict__ s2, const float* __restrict__ pw,
                       const float* __restrict__ pb, float4* __restrict__ out) {
    const int total = N_NODES * NC4;
    float w = pw[2 * D_FEAT];
    float b = pb[0];
    for (int idx = blockIdx.x * blockDim.x + threadIdx.x; idx < total;
         idx += gridDim.x * blockDim.x) {
        int i = idx / NC4;
        int j4 = idx - i * NC4;
        float4 dv = dis[idx];
        float base = s2[i] + b;
        int j = j4 * 4;
        float4 o;
        o.x = tanhf(base + s1[j + 0] + dv.x * w);
        o.y = tanhf(base + s1[j + 1] + dv.y * w);
        o.z = tanhf(base + s1[j + 2] + dv.z * w);
        o.w = tanhf(base + s1[j + 3] + dv.w * w);
        out[idx] = o;
    }
}

extern "C" void kernel_launch(void* const* d_in, const int* in_sizes, int n_in,
                              void* d_out, int out_size, void* d_ws, size_t ws_size,
                              hipStream_t stream) {
    const float* nfeats = (const float*)d_in[0];
    const float* dis    = (const float*)d_in[1];
    const int*   src    = (const int*)d_in[2];
    const int*   dst    = (const int*)d_in[3];
    const float* w[4]  = {(const float*)d_in[4],  (const float*)d_in[8],
                          (const float*)d_in[12], (const float*)d_in[16]};
    const float* al[4] = {(const float*)d_in[5],  (const float*)d_in[9],
                          (const float*)d_in[13], (const float*)d_in[17]};
    const float* ar[4] = {(const float*)d_in[6],  (const float*)d_in[10],
                          (const float*)d_in[14], (const float*)d_in[18]};
    const float* bs[4] = {(const float*)d_in[7],  (const float*)d_in[11],
                          (const float*)d_in[15], (const float*)d_in[19]};
    const float* pw = (const float*)d_in[20];
    const float* pb = (const float*)d_in[21];
    float* out = (float*)d_out;

    // workspace layout
    float* f    = (float*)d_ws;                 // N*HD
    float* hbuf = f + N_NODES * HD;             // N*HD
    float* el   = hbuf + N_NODES * HD;          // N*H
    float* er   = el + N_NODES * H_HEADS;       // N*H
    float* s1   = er + N_NODES * H_HEADS;       // N
    float* s2   = s1 + N_NODES;                 // N
    int* row_ptr = (int*)(s2 + N_NODES);        // N+1
    int* cursor  = row_ptr + (N_NODES + 1);     // N
    int* csrc    = cursor + N_NODES;            // E (source node id, grouped by dst)

    // CSR build (dst-indexed)
    hipMemsetAsync(cursor, 0, N_NODES * sizeof(int), stream);
    k_count<<<(E_EDGES + 255) / 256, 256, 0, stream>>>(dst, cursor);
    k_scan<<<1, 1024, 0, stream>>>(cursor, row_ptr);
    k_fill<<<(E_EDGES + 255) / 256, 256, 0, stream>>>(src, dst, row_ptr, cursor, csrc);

    const float* hin = nfeats;
    for (int l = 0; l < 4; l++) {
        int K = (l == 0) ? IN_FEAT : HD;
        dim3 g(HD / 32, (N_NODES + 31) / 32);
        k_gemm<<<g, 64, 0, stream>>>(hin, w[l], f, N_NODES, K);
        k_elr<<<(N_NODES * H_HEADS + 3) / 4, 256, 0, stream>>>(f, al[l], ar[l], el, er);
        k_agg<<<N_NODES, 384, 0, stream>>>(f, el, er, bs[l], row_ptr, csrc, hbuf,
                                           (l < 3) ? 1 : 0);
        hin = hbuf;
    }
    k_embed<<<(N_NODES + 3) / 4, 256, 0, stream>>>(hbuf, pw, s1, s2);
    k_pair<<<4096, 256, 0, stream>>>((const float4*)dis, s1, s2, pw, pb, (float4*)out);
}